// Round 4
// baseline (3371.942 us; speedup 1.0000x reference)
//
#include <hip/hip_runtime.h>
#include <hip/hip_bf16.h>

// Problem constants
#define Bn 16
#define Sn 16
#define Ln 64
#define En 512
#define Hn 512
#define Nn 512   // B*2*S packed batch
#define G4 2048  // 4*H

typedef __bf16 bf16x8 __attribute__((ext_vector_type(8)));
typedef float f32x4 __attribute__((ext_vector_type(4)));
typedef unsigned short u16x8 __attribute__((ext_vector_type(8)));

__device__ __forceinline__ unsigned short f2bf(float f) {
    union { float f; unsigned u; } v; v.f = f;
    unsigned r = v.u + 0x7FFFu + ((v.u >> 16) & 1u);   // RNE
    return (unsigned short)(r >> 16);
}
__device__ __forceinline__ float bf2f(unsigned short u) {
    union { unsigned u; float f; } v; v.u = ((unsigned)u) << 16;
    return v.f;
}
__device__ __forceinline__ float sigmf(float x) {
    return 1.0f / (1.0f + __expf(-x));
}
__device__ __forceinline__ float tanh_fast(float x) {
    x = fminf(fmaxf(x, -15.0f), 15.0f);
    float e = __expf(2.0f * x);
    return (e - 1.0f) / (e + 1.0f);
}

// ---------------------------------------------------------------------------
// ws layout (bytes):
//   0        .. 2M   : WihImg (bf16, swizzled, [utile32][grow64][512k])
//   2M       .. 4M   : WhhImg
//   4M       .. +8K  : bsum (fp32, 2048)
//   4M+8K    .. +1M  : hImg  (bf16, [par2][ntile8][iter8][row64][64k swz])
//   5251072  .. +1K  : flags (8 clusters x 32 ints, 128B apart)
//   5252096  .. +128K: feat
//   5380096  .. +16K : z1
// ---------------------------------------------------------------------------
#define WS_WIH   0
#define WS_WHH   2097152
#define WS_BSUM  4194304
#define WS_HIMG  4202496
#define WS_FLAGS 5251072
#define WS_FEAT  5252096
#define WS_Z1    5380096

// prep work items: 2*131072 W-chunks + 32768 h-zero-16B + 2048 bsum + 8 flags
#define WCH 131072
#define PREP_TOTAL (2*WCH + 32768 + 2048 + 8)

__global__ __launch_bounds__(256) void prep_kernel(
    const float* __restrict__ Wih_f, const float* __restrict__ Whh_f,
    const float* __restrict__ bih, const float* __restrict__ bhh,
    unsigned short* __restrict__ WihImg, unsigned short* __restrict__ WhhImg,
    float* __restrict__ bsum, unsigned short* __restrict__ hImg0,
    int* __restrict__ flags) {
    int i = blockIdx.x * 256 + threadIdx.x;
    if (i < 2 * WCH) {
        const float* src = (i < WCH) ? Wih_f : Whh_f;
        unsigned short* dst = (i < WCH) ? WihImg : WhhImg;
        int c = (i < WCH) ? i : i - WCH;
        int g4row = c >> 6;              // 0..2047 (gate*512 + unit)
        int chunk = c & 63;              // k>>3
        int unit = g4row & 511;
        int gate = g4row >> 9;
        int utile = unit >> 4;
        int grow = gate * 16 + (unit & 15);
        int phys = chunk ^ (grow & 7);   // low-3-bit XOR: banks 0..28 spread
        const float* s = src + (size_t)g4row * 512 + chunk * 8;
        u16x8 w;
#pragma unroll
        for (int j = 0; j < 8; ++j) w[j] = f2bf(s[j]);
        *(u16x8*)(dst + utile * 32768 + grow * 512 + phys * 8) = w;
    } else if (i < 2 * WCH + 32768) {
        int j = i - 2 * WCH;
        u16x8 z = {0, 0, 0, 0, 0, 0, 0, 0};
        *(u16x8*)(hImg0 + j * 8) = z;    // zero par0 (h0 = 0)
    } else if (i < 2 * WCH + 32768 + 2048) {
        int j = i - (2 * WCH + 32768);
        bsum[j] = bih[j] + bhh[j];
    } else if (i < PREP_TOTAL) {
        int j = i - (2 * WCH + 32768 + 2048);
        flags[j * 32] = 0;
    }
}

// ---------------------------------------------------------------------------
// Persistent LSTM: 256 WGs (= 8 n-clusters x 32 u-tiles), 512 threads.
// Launched via hipLaunchCooperativeKernel => co-residency guaranteed.
// All 64 timesteps inside one kernel. W_ih/W_hh slices LDS-resident.
// Waves 0-3: x-part GEMM; waves 4-7: h-part GEMM; combine via LDS dumps.
// Cluster sync: monotonic counter, release-add / bounded relaxed-spin+acquire.
// ---------------------------------------------------------------------------
__global__ __launch_bounds__(512, 1) void lstm_persist(
    const float* __restrict__ xf, const float* __restrict__ xa,
    const unsigned short* __restrict__ WihImg,
    const unsigned short* __restrict__ WhhImg,
    const float* __restrict__ bsum,
    unsigned short* __restrict__ hImg, int* __restrict__ flags) {
    __shared__ __align__(16) char smem[163840];
    char* WihL  = smem;              // 64KB
    char* WhhL  = smem + 65536;      // 64KB
    char* xbuf0 = smem + 131072;     // 8KB
    char* xbuf1 = smem + 139264;     // 8KB
    char* hbuf0 = smem + 147456;     // 8KB
    char* hbuf1 = smem + 155648;     // 8KB
    float* xdump = (float*)(smem + 131072);  // 16KB overlay on xbuf0/1
    float* hdump = (float*)(smem + 147456);  // 16KB overlay on hbuf0/1

    const int tid = threadIdx.x;
    const int bid = blockIdx.x;
    const int ntile = bid & 7;       // cluster: all 32 WGs land on one XCD
    const int utile = bid >> 3;      // 0..31
    const int n0 = ntile * 64;
    const int u0 = utile * 16;

    // ---- W slices -> LDS (linear copy; images pre-swizzled)
    {
        const unsigned short* wi = WihImg + utile * 32768;
        const unsigned short* wh = WhhImg + utile * 32768;
#pragma unroll
        for (int rnd = 0; rnd < 8; ++rnd) {
            int off = rnd * 4096 + tid * 8;   // u16 index
            *(u16x8*)(WihL + off * 2) = *(const u16x8*)(wi + off);
            *(u16x8*)(WhhL + off * 2) = *(const u16x8*)(wh + off);
        }
    }

    // compute roles
    const int lane = tid & 63;
    const int wv = tid >> 6;         // 0..7
    const int part = wv >> 2;        // 0 = x-part, 1 = h-part
    const int rb = (wv >> 1) & 1;    // out row-block (32 rows)
    const int cb = wv & 1;           // out col-block (32 gate-cols)
    const int l15 = lane & 15;
    const int sel = lane >> 4;       // 0..3
    const int swzA = l15 & 7;

    // staging roles (all 512 threads stage both x and h chunks)
    const int srow = tid >> 3;       // 0..63
    const int sseg = tid & 7;
    const int sphys = sseg ^ (srow & 7);

    const int n_st = n0 + srow;
    const int bb = n_st >> 5, rr = n_st & 31;
    const float* xrow = (rr < Sn)
        ? xf + ((size_t)(bb * Sn + rr) * Ln) * En
        : xa + ((size_t)(bb * Sn + (rr - Sn)) * Ln) * En;

    // cell roles: thread handles cells (crow, cj) and (crow+32, cj)
    const int crow = tid >> 4;       // 0..31
    const int cj = tid & 15;
    const float bI = bsum[u0 + cj];
    const float bF = bsum[512 + u0 + cj];
    const float bG = bsum[1024 + u0 + cj];
    const float bO = bsum[1536 + u0 + cj];
    float cA = 0.0f, cB = 0.0f;
    const int k6 = (utile & 3) * 16 + cj;    // unit pos within 64k iter-chunk
    const int hit = utile >> 2;              // which iter-chunk holds our units

    int* cnt = flags + ntile * 32;

    __syncthreads();   // W resident

    for (int t = 0; t < Ln; ++t) {
        // ---- cluster sync: wait for all 32 producers of step t-1 (bounded)
        if (t > 0 && tid == 0) {
            const int target = 32 * t;
            int guard = 1 << 22;
            while (__hip_atomic_load(cnt, __ATOMIC_RELAXED,
                                     __HIP_MEMORY_SCOPE_AGENT) < target &&
                   --guard)
                __builtin_amdgcn_s_sleep(2);
            (void)__hip_atomic_load(cnt, __ATOMIC_ACQUIRE,
                                    __HIP_MEMORY_SCOPE_AGENT);
        }
        __syncthreads();

        const unsigned short* hIn = hImg + (size_t)(t & 1) * 262144 + ntile * 32768;
        const float* xt = xrow + (size_t)t * En;

        f32x4 acc[4];
#pragma unroll
        for (int f = 0; f < 4; ++f) acc[f] = (f32x4){0.f, 0.f, 0.f, 0.f};

        // ---- prologue: stage iter 0
        {
            float4 v0 = *(const float4*)(xt + sseg * 8);
            float4 v1 = *(const float4*)(xt + sseg * 8 + 4);
            u16x8 w;
            w[0] = f2bf(v0.x); w[1] = f2bf(v0.y); w[2] = f2bf(v0.z); w[3] = f2bf(v0.w);
            w[4] = f2bf(v1.x); w[5] = f2bf(v1.y); w[6] = f2bf(v1.z); w[7] = f2bf(v1.w);
            *(u16x8*)(xbuf0 + srow * 128 + sphys * 16) = w;
            *(u16x8*)(hbuf0 + tid * 16) = *(const u16x8*)(hIn + tid * 8);
        }
        __syncthreads();

        // ---- k-loop: 8 iters of BK=64, double-buffered
#pragma unroll
        for (int it = 0; it < 8; ++it) {
            char* xcur = (it & 1) ? xbuf1 : xbuf0;
            char* hcur = (it & 1) ? hbuf1 : hbuf0;
            char* xnxt = (it & 1) ? xbuf0 : xbuf1;
            char* hnxt = (it & 1) ? hbuf0 : hbuf1;
            float4 v0, v1;
            u16x8 hv;
            if (it < 7) {
                v0 = *(const float4*)(xt + (it + 1) * 64 + sseg * 8);
                v1 = *(const float4*)(xt + (it + 1) * 64 + sseg * 8 + 4);
                hv = *(const u16x8*)(hIn + (it + 1) * 4096 + tid * 8);
            }
            // compute current buffer
            const char* A = part ? hcur : xcur;
            const char* Wl = part ? WhhL : WihL;
#pragma unroll
            for (int kk = 0; kk < 2; ++kk) {
                const int chunkA = (kk * 4 + sel) ^ swzA;
                bf16x8 a0 = *(const bf16x8*)(A + (rb * 32 + l15) * 128 + chunkA * 16);
                bf16x8 a1 = *(const bf16x8*)(A + (rb * 32 + 16 + l15) * 128 + chunkA * 16);
#pragma unroll
                for (int cf = 0; cf < 2; ++cf) {
                    const int gcol = cb * 32 + cf * 16 + l15;
                    const int chunkB = (it * 8 + kk * 4 + sel) ^ (gcol & 7);
                    bf16x8 b = *(const bf16x8*)(Wl + gcol * 1024 + chunkB * 16);
                    acc[cf] = __builtin_amdgcn_mfma_f32_16x16x32_bf16(a0, b, acc[cf], 0, 0, 0);
                    acc[2 + cf] = __builtin_amdgcn_mfma_f32_16x16x32_bf16(a1, b, acc[2 + cf], 0, 0, 0);
                }
            }
            // write next stage
            if (it < 7) {
                u16x8 w;
                w[0] = f2bf(v0.x); w[1] = f2bf(v0.y); w[2] = f2bf(v0.z); w[3] = f2bf(v0.w);
                w[4] = f2bf(v1.x); w[5] = f2bf(v1.y); w[6] = f2bf(v1.z); w[7] = f2bf(v1.w);
                *(u16x8*)(xnxt + srow * 128 + sphys * 16) = w;
                *(u16x8*)(hnxt + tid * 16) = hv;
            }
            __syncthreads();
        }

        // ---- dump accs to LDS (chunk buffers are free now)
        {
            float* dmp = part ? hdump : xdump;
#pragma unroll
            for (int rf = 0; rf < 2; ++rf)
#pragma unroll
                for (int cf = 0; cf < 2; ++cf)
#pragma unroll
                    for (int q = 0; q < 4; ++q) {
                        const int row = rb * 32 + rf * 16 + sel * 4 + q;
                        const int col = cb * 32 + cf * 16 + l15;
                        dmp[row * 64 + col] = acc[rf * 2 + cf][q];
                    }
        }
        __syncthreads();

        // ---- cell phase: 2 cells per thread, c in registers
        {
            unsigned short* hOut = hImg + (size_t)((t + 1) & 1) * 262144 + ntile * 32768;
#pragma unroll
            for (int half = 0; half < 2; ++half) {
                const int r = crow + half * 32;
                const float I = sigmf(xdump[r * 64 + cj] + hdump[r * 64 + cj] + bI);
                const float F = sigmf(xdump[r * 64 + 16 + cj] + hdump[r * 64 + 16 + cj] + bF);
                const float G = tanh_fast(xdump[r * 64 + 32 + cj] + hdump[r * 64 + 32 + cj] + bG);
                const float O = sigmf(xdump[r * 64 + 48 + cj] + hdump[r * 64 + 48 + cj] + bO);
                float cc = half ? cB : cA;
                cc = F * cc + I * G;
                if (half) cB = cc; else cA = cc;
                const float hval = O * tanh_fast(cc);
                hOut[hit * 4096 + r * 64 + (((k6 >> 3) ^ (r & 7)) * 8) + (k6 & 7)] = f2bf(hval);
            }
        }
        __threadfence();
        __syncthreads();
        if (tid == 0)
            __hip_atomic_fetch_add(cnt, 1, __ATOMIC_RELEASE, __HIP_MEMORY_SCOPE_AGENT);
    }
}

// ---------------------------------------------------------------------------
// Head: pool (de-swizzling image reads), fc1, fc2.
// ---------------------------------------------------------------------------
__global__ __launch_bounds__(256) void pool_kernel(
    const unsigned short* __restrict__ hImg, float* __restrict__ feat) {
    const int blk = blockIdx.x;      // 32 = (b, side)
    const int b = blk >> 1, side = blk & 1;
    const int tid = threadIdx.x;
    for (int u = tid; u < Hn; u += 256) {
        const int it = u >> 6, k6 = u & 63;
        float s = 0.0f, m = -1e30f;
#pragma unroll
        for (int ss = 0; ss < Sn; ++ss) {
            const int n = b * 32 + side * 16 + ss;
            const int nt = n >> 6, r = n & 63;
            float v = bf2f(hImg[nt * 32768 + it * 4096 + r * 64 +
                                (((k6 >> 3) ^ (r & 7)) * 8) + (k6 & 7)]);
            s += v;
            m = fmaxf(m, v);
        }
        feat[b * 2048 + side * 1024 + u] = s * (1.0f / 16.0f);
        feat[b * 2048 + side * 1024 + 512 + u] = m;
    }
}

__global__ __launch_bounds__(256) void fc1_kernel(
    const float* __restrict__ feat, const float* __restrict__ fc1w,
    const float* __restrict__ fc1b, float* __restrict__ z1) {
    __shared__ float fs[2048];
    __shared__ float red[256];
    const int b = blockIdx.x >> 4, oc = blockIdx.x & 15;
    const int tid = threadIdx.x;
    for (int k = tid; k < 2048; k += 256) fs[k] = feat[b * 2048 + k];
    __syncthreads();
    const int o = oc * 16 + (tid & 15);
    const int ks = (tid >> 4) * 128;
    const float4* w4 = (const float4*)(fc1w + (size_t)o * 2048 + ks);
    const float* fr = fs + ks;
    float p = 0.0f;
#pragma unroll 8
    for (int k = 0; k < 32; ++k) {
        float4 w = w4[k];
        p += fr[k * 4] * w.x + fr[k * 4 + 1] * w.y +
             fr[k * 4 + 2] * w.z + fr[k * 4 + 3] * w.w;
    }
    red[(tid & 15) * 16 + (tid >> 4)] = p;
    __syncthreads();
    if (tid < 16) {
        float z = fc1b[oc * 16 + tid];
#pragma unroll
        for (int j = 0; j < 16; ++j) z += red[tid * 16 + j];
        z1[b * 256 + oc * 16 + tid] = z;
    }
}

__global__ __launch_bounds__(256) void fc2_kernel(
    const float* __restrict__ z1, const float* __restrict__ fc2w,
    const float* __restrict__ fc2b, float* __restrict__ out) {
    __shared__ float sh[256];
    const int b = blockIdx.x, tid = threadIdx.x;
    sh[tid] = z1[b * 256 + tid] * fc2w[tid];
    __syncthreads();
    for (int s = 128; s > 0; s >>= 1) {
        if (tid < s) sh[tid] += sh[tid + s];
        __syncthreads();
    }
    if (tid == 0) out[b] = sigmf(sh[0] + fc2b[0]);
}

// ---------------------------------------------------------------------------
extern "C" void kernel_launch(void* const* d_in, const int* in_sizes, int n_in,
                              void* d_out, int out_size, void* d_ws, size_t ws_size,
                              hipStream_t stream) {
    const float* xf    = (const float*)d_in[0];
    const float* xa    = (const float*)d_in[1];
    const float* Wih_f = (const float*)d_in[2];
    const float* Whh_f = (const float*)d_in[3];
    const float* bih   = (const float*)d_in[4];
    const float* bhh   = (const float*)d_in[5];
    const float* fc1w  = (const float*)d_in[6];
    const float* fc1b  = (const float*)d_in[7];
    const float* fc2w  = (const float*)d_in[8];
    const float* fc2b  = (const float*)d_in[9];
    float* out = (float*)d_out;

    char* ws = (char*)d_ws;
    unsigned short* WihImg = (unsigned short*)(ws + WS_WIH);
    unsigned short* WhhImg = (unsigned short*)(ws + WS_WHH);
    float*          bsum   = (float*)(ws + WS_BSUM);
    unsigned short* hImg   = (unsigned short*)(ws + WS_HIMG);
    int*            flags  = (int*)(ws + WS_FLAGS);
    float*          feat   = (float*)(ws + WS_FEAT);
    float*          z1     = (float*)(ws + WS_Z1);

    prep_kernel<<<dim3((PREP_TOTAL + 255) / 256), dim3(256), 0, stream>>>(
        Wih_f, Whh_f, bih, bhh, WihImg, WhhImg, bsum, hImg, flags);

    // Cooperative launch: guarantees all 256 WGs co-resident (or fails loudly).
    {
        const float* a0 = xf; const float* a1 = xa;
        const unsigned short* a2 = WihImg; const unsigned short* a3 = WhhImg;
        const float* a4 = bsum; unsigned short* a5 = hImg; int* a6 = flags;
        void* args[] = {&a0, &a1, &a2, &a3, &a4, &a5, &a6};
        (void)hipLaunchCooperativeKernel((const void*)lstm_persist,
                                         dim3(256), dim3(512), args, 0, stream);
    }

    // final h (t=63) is in parity 0 of hImg
    pool_kernel<<<dim3(32), dim3(256), 0, stream>>>(hImg, feat);
    fc1_kernel<<<dim3(256), dim3(256), 0, stream>>>(feat, fc1w, fc1b, z1);
    fc2_kernel<<<dim3(16), dim3(256), 0, stream>>>(z1, fc2w, fc2b, out);
}

// Round 5
// 1227.727 us; speedup vs baseline: 2.7465x; 2.7465x over previous
//
#include <hip/hip_runtime.h>
#include <hip/hip_bf16.h>

// Problem constants
#define Bn 16
#define Sn 16
#define Ln 64
#define En 512
#define Hn 512
#define Nn 512   // B*2*S packed batch
#define G4 2048  // 4*H

typedef __bf16 bf16x8 __attribute__((ext_vector_type(8)));
typedef float f32x4 __attribute__((ext_vector_type(4)));
typedef unsigned short u16x8 __attribute__((ext_vector_type(8)));

__device__ __forceinline__ unsigned short f2bf(float f) {
    union { float f; unsigned u; } v; v.f = f;
    unsigned r = v.u + 0x7FFFu + ((v.u >> 16) & 1u);   // RNE
    return (unsigned short)(r >> 16);
}
__device__ __forceinline__ float bf2f(unsigned short u) {
    union { unsigned u; float f; } v; v.u = ((unsigned)u) << 16;
    return v.f;
}
__device__ __forceinline__ float sigmf(float x) {
    return 1.0f / (1.0f + __expf(-x));
}
__device__ __forceinline__ float tanh_fast(float x) {
    x = fminf(fmaxf(x, -15.0f), 15.0f);
    float e = __expf(2.0f * x);
    return (e - 1.0f) / (e + 1.0f);
}

// ---------------------------------------------------------------------------
// ws layout (bytes):
//   WihImg  [ut 32][grow 64][k 512] bf16 (grow = gate*16 + unit%16)   2MB
//   WhhImg  same                                                      2MB
//   bsum    fp32 [gate*512 + unit]                                    8KB
//   hA/hB   bf16 [n 512][k 512] linear                                512KB x2
//   c       fp32 [n 512][unit 512]                                    1MB
//   feat / z1                                                         144KB
//   Xg      bf16 [t 64][ut 32][nt 8][row 64][grow 64]                 134MB
// ---------------------------------------------------------------------------
#define WS_WIH   0
#define WS_WHH   2097152
#define WS_BSUM  4194304
#define WS_HA    4202496
#define WS_HB    4726784
#define WS_C     5251072
#define WS_FEAT  6299648
#define WS_Z1    6430720
#define WS_XG    6447104

// prep work items
#define WCH 131072        // W u16x8-chunks per matrix
#define HZ16 32768        // hA zero (16B units)
#define CZ16 65536        // c zero (16B units)
#define PREP_TOTAL (2*WCH + HZ16 + CZ16 + 2048)

__global__ __launch_bounds__(256) void prep_kernel(
    const float* __restrict__ Wih_f, const float* __restrict__ Whh_f,
    const float* __restrict__ bih, const float* __restrict__ bhh,
    unsigned short* __restrict__ WihImg, unsigned short* __restrict__ WhhImg,
    float* __restrict__ bsum, unsigned short* __restrict__ hA,
    float* __restrict__ c) {
    int i = blockIdx.x * 256 + threadIdx.x;
    if (i < 2 * WCH) {
        const float* src = (i < WCH) ? Wih_f : Whh_f;
        unsigned short* dst = (i < WCH) ? WihImg : WhhImg;
        int cc = (i < WCH) ? i : i - WCH;
        int g4row = cc >> 6;             // gate*512 + unit
        int chunk = cc & 63;
        int gate = g4row >> 9, unit = g4row & 511;
        int ut = unit >> 4, u15 = unit & 15;
        int grow = gate * 16 + u15;
        const float* s = src + (size_t)g4row * 512 + chunk * 8;
        u16x8 w;
#pragma unroll
        for (int j = 0; j < 8; ++j) w[j] = f2bf(s[j]);
        *(u16x8*)(dst + ut * 32768 + grow * 512 + chunk * 8) = w;
    } else if (i < 2 * WCH + HZ16) {
        int j = i - 2 * WCH;
        u16x8 z = {0, 0, 0, 0, 0, 0, 0, 0};
        *(u16x8*)(hA + j * 8) = z;
    } else if (i < 2 * WCH + HZ16 + CZ16) {
        int j = i - (2 * WCH + HZ16);
        f32x4 z = {0.f, 0.f, 0.f, 0.f};
        *(f32x4*)(c + j * 4) = z;
    } else if (i < PREP_TOTAL) {
        int j = i - (2 * WCH + HZ16 + CZ16);
        bsum[j] = bih[j] + bhh[j];
    }
}

// ---------------------------------------------------------------------------
// Phase 1: Xg[t][ut][nt][row][grow] = (x[n,t,:] @ W_ih^T) in bf16.
// Grid 512 (= n), block 256 (4 waves). x row-block staged once in LDS
// (64 t-rows x 512 k, bf16, chunk^row&7 swizzle); W_ih read as direct
// global fragments (L2-resident, broadcast). 32 ut-rounds per WG.
// ---------------------------------------------------------------------------
__global__ __launch_bounds__(256) void xg_gemm(
    const float* __restrict__ xf, const float* __restrict__ xa,
    const unsigned short* __restrict__ WihImg,
    unsigned short* __restrict__ Xg) {
    __shared__ __align__(16) unsigned short xs[64 * 512];  // 64KB

    const int n = blockIdx.x;
    const int tid = threadIdx.x;
    const int bb = n >> 5, r5 = n & 31;
    const float* xbase = (r5 < Sn)
        ? xf + (size_t)(bb * Sn + r5) * Ln * En
        : xa + (size_t)(bb * Sn + (r5 - Sn)) * Ln * En;

    // stage [t 64][k 512] -> bf16 LDS, swizzled
    {
        const int r = tid >> 2, seg = tid & 3;
        const float* src = xbase + (size_t)r * En;
#pragma unroll
        for (int cc = 0; cc < 16; ++cc) {
            const int chunk = seg * 16 + cc;
            float4 v0 = *(const float4*)(src + chunk * 8);
            float4 v1 = *(const float4*)(src + chunk * 8 + 4);
            u16x8 w;
            w[0] = f2bf(v0.x); w[1] = f2bf(v0.y); w[2] = f2bf(v0.z); w[3] = f2bf(v0.w);
            w[4] = f2bf(v1.x); w[5] = f2bf(v1.y); w[6] = f2bf(v1.z); w[7] = f2bf(v1.w);
            *(u16x8*)(xs + r * 512 + ((chunk ^ (r & 7)) * 8)) = w;
        }
    }
    __syncthreads();

    const int lane = tid & 63, w = tid >> 6;
    const int l15 = lane & 15, sel = lane >> 4;
    const int arow = w * 16 + l15;
    const int aswz = l15 & 7;
    const int nt = n >> 6, r64 = n & 63;

    for (int ut = 0; ut < 32; ++ut) {
        f32x4 acc[4];
#pragma unroll
        for (int g = 0; g < 4; ++g) acc[g] = (f32x4){0.f, 0.f, 0.f, 0.f};
        const unsigned short* wb = WihImg + ut * 32768;
#pragma unroll 4
        for (int kb = 0; kb < 16; ++kb) {
            bf16x8 a = *(const bf16x8*)(xs + arow * 512 + (((kb * 4 + sel) ^ aswz) * 8));
#pragma unroll
            for (int g = 0; g < 4; ++g) {
                bf16x8 b = *(const bf16x8*)(wb + (g * 16 + l15) * 512 + kb * 32 + sel * 8);
                acc[g] = __builtin_amdgcn_mfma_f32_16x16x32_bf16(a, b, acc[g], 0, 0, 0);
            }
        }
#pragma unroll
        for (int g = 0; g < 4; ++g)
#pragma unroll
            for (int q = 0; q < 4; ++q) {
                const int t = w * 16 + sel * 4 + q;
                const size_t idx = ((((size_t)t * 32 + ut) * 8 + nt) * 64 + r64) * 64
                                 + g * 16 + l15;
                Xg[idx] = f2bf(acc[g][q]);
            }
    }
}

// ---------------------------------------------------------------------------
// One LSTM step: gates = Xg[t] + h @ W_hh^T, then cell.
// Grid 256 (8 nt x 32 ut), block 512 (8 waves). No GEMM LDS staging:
// A (h) and B (W_hh) fragments are direct global u16x8 loads (L2-hot).
// K=512 split across wave halves (grp); reduce via LDS dumps; fused cell.
// ---------------------------------------------------------------------------
__global__ __launch_bounds__(512) void lstm_step(
    const unsigned short* __restrict__ Whh, const unsigned short* __restrict__ Xg,
    const float* __restrict__ bsum,
    const unsigned short* __restrict__ h_in, unsigned short* __restrict__ h_out,
    float* __restrict__ c, int t) {
    __shared__ float dump[2][64 * 64];   // 32KB

    const int tid = threadIdx.x;
    const int bid = blockIdx.x;
    const int nt = bid & 7, ut = bid >> 3;   // nt fast => cluster on one XCD
    const int n0 = nt * 64, u0 = ut * 16;
    const int lane = tid & 63, wv = tid >> 6;
    const int grp = wv >> 2;                 // k-half
    const int w = wv & 3;                    // 16-row block
    const int l15 = lane & 15, sel = lane >> 4;

    f32x4 acc[4];
#pragma unroll
    for (int g = 0; g < 4; ++g) acc[g] = (f32x4){0.f, 0.f, 0.f, 0.f};

    const unsigned short* hrow = h_in + (size_t)(n0 + w * 16 + l15) * 512 + grp * 256;
    const unsigned short* wb = Whh + ut * 32768 + grp * 256;

#pragma unroll 4
    for (int kb = 0; kb < 8; ++kb) {
        bf16x8 a = *(const bf16x8*)(hrow + kb * 32 + sel * 8);
#pragma unroll
        for (int g = 0; g < 4; ++g) {
            bf16x8 b = *(const bf16x8*)(wb + (g * 16 + l15) * 512 + kb * 32 + sel * 8);
            acc[g] = __builtin_amdgcn_mfma_f32_16x16x32_bf16(a, b, acc[g], 0, 0, 0);
        }
    }
    // dump partial sums
#pragma unroll
    for (int g = 0; g < 4; ++g)
#pragma unroll
        for (int q = 0; q < 4; ++q)
            dump[grp][(w * 16 + sel * 4 + q) * 64 + g * 16 + l15] = acc[g][q];
    __syncthreads();

    // cell phase: 1024 cells / 512 threads = 2 each
    const int crow = tid >> 4, cj = tid & 15;
    const float bI = bsum[u0 + cj];
    const float bF = bsum[512 + u0 + cj];
    const float bG = bsum[1024 + u0 + cj];
    const float bO = bsum[1536 + u0 + cj];
    const unsigned short* xgt = Xg + (((size_t)t * 32 + ut) * 8 + nt) * 4096;
#pragma unroll
    for (int half = 0; half < 2; ++half) {
        const int r = crow + half * 32;
        const float gi = dump[0][r * 64 + cj]      + dump[1][r * 64 + cj]
                       + bf2f(xgt[r * 64 + cj]) + bI;
        const float gf = dump[0][r * 64 + 16 + cj] + dump[1][r * 64 + 16 + cj]
                       + bf2f(xgt[r * 64 + 16 + cj]) + bF;
        const float gg = dump[0][r * 64 + 32 + cj] + dump[1][r * 64 + 32 + cj]
                       + bf2f(xgt[r * 64 + 32 + cj]) + bG;
        const float go = dump[0][r * 64 + 48 + cj] + dump[1][r * 64 + 48 + cj]
                       + bf2f(xgt[r * 64 + 48 + cj]) + bO;
        const size_t ci = (size_t)(n0 + r) * 512 + u0 + cj;
        const float I = sigmf(gi), F = sigmf(gf);
        const float G = tanh_fast(gg), O = sigmf(go);
        const float cn = F * c[ci] + I * G;
        c[ci] = cn;
        h_out[ci] = f2bf(O * tanh_fast(cn));
    }
}

// ---------------------------------------------------------------------------
// Head: pool, fc1, fc2 (R2-proven).
// ---------------------------------------------------------------------------
__global__ __launch_bounds__(256) void pool_kernel(
    const unsigned short* __restrict__ hfin, float* __restrict__ feat) {
    const int blk = blockIdx.x;
    const int b = blk >> 1, side = blk & 1;
    const int tid = threadIdx.x;
    for (int u = tid; u < Hn; u += 256) {
        float s = 0.0f, m = -1e30f;
#pragma unroll
        for (int ss = 0; ss < Sn; ++ss) {
            float v = bf2f(hfin[(size_t)(b * 32 + side * 16 + ss) * 512 + u]);
            s += v;
            m = fmaxf(m, v);
        }
        feat[b * 2048 + side * 1024 + u] = s * (1.0f / 16.0f);
        feat[b * 2048 + side * 1024 + 512 + u] = m;
    }
}

__global__ __launch_bounds__(256) void fc1_kernel(
    const float* __restrict__ feat, const float* __restrict__ fc1w,
    const float* __restrict__ fc1b, float* __restrict__ z1) {
    __shared__ float fs[2048];
    __shared__ float red[256];
    const int b = blockIdx.x >> 4, oc = blockIdx.x & 15;
    const int tid = threadIdx.x;
    for (int k = tid; k < 2048; k += 256) fs[k] = feat[b * 2048 + k];
    __syncthreads();
    const int o = oc * 16 + (tid & 15);
    const int ks = (tid >> 4) * 128;
    const float4* w4 = (const float4*)(fc1w + (size_t)o * 2048 + ks);
    const float* fr = fs + ks;
    float p = 0.0f;
#pragma unroll 8
    for (int k = 0; k < 32; ++k) {
        float4 w = w4[k];
        p += fr[k * 4] * w.x + fr[k * 4 + 1] * w.y +
             fr[k * 4 + 2] * w.z + fr[k * 4 + 3] * w.w;
    }
    red[(tid & 15) * 16 + (tid >> 4)] = p;
    __syncthreads();
    if (tid < 16) {
        float z = fc1b[oc * 16 + tid];
#pragma unroll
        for (int j = 0; j < 16; ++j) z += red[tid * 16 + j];
        z1[b * 256 + oc * 16 + tid] = z;
    }
}

__global__ __launch_bounds__(256) void fc2_kernel(
    const float* __restrict__ z1, const float* __restrict__ fc2w,
    const float* __restrict__ fc2b, float* __restrict__ out) {
    __shared__ float sh[256];
    const int b = blockIdx.x, tid = threadIdx.x;
    sh[tid] = z1[b * 256 + tid] * fc2w[tid];
    __syncthreads();
    for (int s = 128; s > 0; s >>= 1) {
        if (tid < s) sh[tid] += sh[tid + s];
        __syncthreads();
    }
    if (tid == 0) out[b] = sigmf(sh[0] + fc2b[0]);
}

// ---------------------------------------------------------------------------
extern "C" void kernel_launch(void* const* d_in, const int* in_sizes, int n_in,
                              void* d_out, int out_size, void* d_ws, size_t ws_size,
                              hipStream_t stream) {
    const float* xf    = (const float*)d_in[0];
    const float* xa    = (const float*)d_in[1];
    const float* Wih_f = (const float*)d_in[2];
    const float* Whh_f = (const float*)d_in[3];
    const float* bih   = (const float*)d_in[4];
    const float* bhh   = (const float*)d_in[5];
    const float* fc1w  = (const float*)d_in[6];
    const float* fc1b  = (const float*)d_in[7];
    const float* fc2w  = (const float*)d_in[8];
    const float* fc2b  = (const float*)d_in[9];
    float* out = (float*)d_out;

    char* ws = (char*)d_ws;
    unsigned short* WihImg = (unsigned short*)(ws + WS_WIH);
    unsigned short* WhhImg = (unsigned short*)(ws + WS_WHH);
    float*          bsum   = (float*)(ws + WS_BSUM);
    unsigned short* hA     = (unsigned short*)(ws + WS_HA);
    unsigned short* hB     = (unsigned short*)(ws + WS_HB);
    float*          cbuf   = (float*)(ws + WS_C);
    float*          feat   = (float*)(ws + WS_FEAT);
    float*          z1     = (float*)(ws + WS_Z1);
    unsigned short* Xg     = (unsigned short*)(ws + WS_XG);

    prep_kernel<<<dim3((PREP_TOTAL + 255) / 256), dim3(256), 0, stream>>>(
        Wih_f, Whh_f, bih, bhh, WihImg, WhhImg, bsum, hA, cbuf);

    xg_gemm<<<dim3(Nn), dim3(256), 0, stream>>>(xf, xa, WihImg, Xg);

    for (int t = 0; t < Ln; ++t) {
        const unsigned short* hin = (t & 1) ? hB : hA;
        unsigned short* hout      = (t & 1) ? hA : hB;
        lstm_step<<<dim3(256), dim3(512), 0, stream>>>(
            WhhImg, Xg, bsum, hin, hout, cbuf, t);
    }
    // t=63 wrote hA
    pool_kernel<<<dim3(32), dim3(256), 0, stream>>>(hA, feat);
    fc1_kernel<<<dim3(256), dim3(256), 0, stream>>>(feat, fc1w, fc1b, z1);
    fc2_kernel<<<dim3(16), dim3(256), 0, stream>>>(z1, fc2w, fc2b, out);
}

// Round 7
// 460.200 us; speedup vs baseline: 7.3271x; 2.6678x over previous
//
#include <hip/hip_runtime.h>
#include <hip/hip_bf16.h>

// Problem constants
#define Bn 16
#define Sn 16
#define Ln 64
#define En 512
#define Hn 512
#define Nn 512   // B*2*S packed batch
#define G4 2048  // 4*H

typedef __bf16 bf16x8 __attribute__((ext_vector_type(8)));
typedef float f32x4 __attribute__((ext_vector_type(4)));
typedef unsigned short u16x8 __attribute__((ext_vector_type(8)));

__device__ __forceinline__ unsigned short f2bf(float f) {
    union { float f; unsigned u; } v; v.f = f;
    unsigned r = v.u + 0x7FFFu + ((v.u >> 16) & 1u);   // RNE
    return (unsigned short)(r >> 16);
}
__device__ __forceinline__ float bf2f(unsigned short u) {
    union { unsigned u; float f; } v; v.u = ((unsigned)u) << 16;
    return v.f;
}
__device__ __forceinline__ float sigmf(float x) {
    return 1.0f / (1.0f + __expf(-x));
}
__device__ __forceinline__ float tanh_fast(float x) {
    x = fminf(fmaxf(x, -15.0f), 15.0f);
    float e = __expf(2.0f * x);
    return (e - 1.0f) / (e + 1.0f);
}

// ---------------------------------------------------------------------------
// ws layout (bytes)
// ---------------------------------------------------------------------------
#define WS_WIHB  0            // Wih bf16 [gcol 2048][k 512], chunk^(gcol&7) swizzle  2MB
#define WS_WHH   2097152      // Whh image [ut 32][grow 64][k 512], chunk^(grow&7)    2MB
#define WS_BSUM  4194304      // fp32 2048
#define WS_HA    4202496      // h bf16 [n 512][k 512], chunk^(n&7) swizzle   512KB
#define WS_HB    4726784      // 512KB
#define WS_C     5251072      // fp32 [n][u] 1MB
#define WS_FEAT  6299648      // 128KB
#define WS_Z1    6430720      // 16KB
#define WS_XBF   6447104      // x bf16 [m 32768][k 512], chunk^(m&7)  32MB
#define WS_XG    40001536     // Xg bf16 [m 32768][gcol 2048]  134MB  (end ~174MB)

// prep_w work items
#define WI_CH 131072
#define WH_CH 131072
#define HZ 32768
#define CZ 65536
#define PREPW_TOTAL (WI_CH + WH_CH + 2048 + HZ + CZ)

__global__ __launch_bounds__(256) void prep_w(
    const float* __restrict__ Wih_f, const float* __restrict__ Whh_f,
    const float* __restrict__ bih, const float* __restrict__ bhh,
    unsigned short* __restrict__ Wihb, unsigned short* __restrict__ WhhImg,
    float* __restrict__ bsum, unsigned short* __restrict__ hA,
    float* __restrict__ c0) {
    int i = blockIdx.x * 256 + threadIdx.x;
    if (i < WI_CH) {
        int gcol = i >> 6, ch = i & 63;
        const float* s = Wih_f + (size_t)gcol * 512 + ch * 8;
        u16x8 w;
#pragma unroll
        for (int j = 0; j < 8; ++j) w[j] = f2bf(s[j]);
        *(u16x8*)(Wihb + (size_t)gcol * 512 + (ch ^ (gcol & 7)) * 8) = w;
    } else if (i < WI_CH + WH_CH) {
        int j = i - WI_CH;
        int g4row = j >> 6, ch = j & 63;
        int gate = g4row >> 9, unit = g4row & 511;
        int ut = unit >> 4, grow = gate * 16 + (unit & 15);
        const float* s = Whh_f + (size_t)g4row * 512 + ch * 8;
        u16x8 w;
#pragma unroll
        for (int k = 0; k < 8; ++k) w[k] = f2bf(s[k]);
        *(u16x8*)(WhhImg + ut * 32768 + grow * 512 + (ch ^ (grow & 7)) * 8) = w;
    } else if (i < WI_CH + WH_CH + 2048) {
        int j = i - (WI_CH + WH_CH);
        bsum[j] = bih[j] + bhh[j];
    } else if (i < WI_CH + WH_CH + 2048 + HZ) {
        int j = i - (WI_CH + WH_CH + 2048);
        u16x8 z = {0, 0, 0, 0, 0, 0, 0, 0};
        *(u16x8*)(hA + j * 8) = z;
    } else if (i < PREPW_TOTAL) {
        int j = i - (WI_CH + WH_CH + 2048 + HZ);
        f32x4 z = {0.f, 0.f, 0.f, 0.f};
        *(f32x4*)(c0 + j * 4) = z;
    }
}

// x -> bf16 [m][k] (m = t*512 + n), chunk^(m&7) swizzle. 2097152 chunks.
__global__ __launch_bounds__(256) void prep_x(
    const float* __restrict__ xf, const float* __restrict__ xa,
    unsigned short* __restrict__ Xbf) {
    int j = blockIdx.x * 256 + threadIdx.x;
    int m = j >> 6, k8 = j & 63;
    int t = m >> 9, n = m & 511;
    int bb = n >> 5, rr = n & 31;
    const float* src = ((rr < Sn)
        ? xf + ((size_t)(bb * Sn + rr) * Ln + t) * En
        : xa + ((size_t)(bb * Sn + (rr - Sn)) * Ln + t) * En) + k8 * 8;
    float4 v0 = *(const float4*)src;
    float4 v1 = *(const float4*)(src + 4);
    u16x8 w;
    w[0] = f2bf(v0.x); w[1] = f2bf(v0.y); w[2] = f2bf(v0.z); w[3] = f2bf(v0.w);
    w[4] = f2bf(v1.x); w[5] = f2bf(v1.y); w[6] = f2bf(v1.z); w[7] = f2bf(v1.w);
    *(u16x8*)(Xbf + (size_t)m * 512 + (k8 ^ (m & 7)) * 8) = w;
}

// ---------------------------------------------------------------------------
// Xg = Xbf @ Wih^T : M=32768, N=2048, K=512. 128x128 tile, BK=64.
// Grid 4096 = bx(256 m-tiles) + by(16 n-tiles)*256. 256 thr = 4 waves (2x2).
// Reg-staged double-buffered LDS (R2-proven loop), swizzled images.
// ---------------------------------------------------------------------------
__global__ __launch_bounds__(256) void xg_gemm(
    const unsigned short* __restrict__ Xbf,
    const unsigned short* __restrict__ Wihb,
    unsigned short* __restrict__ Xg) {
    __shared__ __align__(16) unsigned short As[2][8192];  // [128][64] x2
    __shared__ __align__(16) unsigned short Bs[2][8192];
    const int tid = threadIdx.x;
    const int bx = blockIdx.x & 255, by = blockIdx.x >> 8;
    const size_t m0 = (size_t)bx * 128;
    const int n0 = by * 128;
    const int wv = tid >> 6, lane = tid & 63;
    const int l15 = lane & 15, sel = lane >> 4;
    const int wm = wv >> 1, wn = wv & 1;

    // staging: 2 threads/row, 32 u16 each
    const int srow = tid >> 1, sseg = tid & 1;
    const unsigned short* asrc = Xbf + (m0 + srow) * 512 + sseg * 32;
    const unsigned short* bsrc = Wihb + (size_t)(n0 + srow) * 512 + sseg * 32;
    const int wofs = srow * 64 + sseg * 32;

    f32x4 acc[4][4];
#pragma unroll
    for (int i = 0; i < 4; ++i)
#pragma unroll
        for (int j = 0; j < 4; ++j) acc[i][j] = (f32x4){0.f, 0.f, 0.f, 0.f};

    u16x8 ar[4], br[4];
#pragma unroll
    for (int r = 0; r < 4; ++r) {
        ar[r] = *(const u16x8*)(asrc + r * 8);
        br[r] = *(const u16x8*)(bsrc + r * 8);
    }

#pragma unroll 1
    for (int it = 0; it < 8; ++it) {
        unsigned short* Ac = As[it & 1];
        unsigned short* Bc = Bs[it & 1];
#pragma unroll
        for (int r = 0; r < 4; ++r) {
            *(u16x8*)(Ac + wofs + r * 8) = ar[r];
            *(u16x8*)(Bc + wofs + r * 8) = br[r];
        }
        if (it < 7) {
#pragma unroll
            for (int r = 0; r < 4; ++r) {
                ar[r] = *(const u16x8*)(asrc + (it + 1) * 64 + r * 8);
                br[r] = *(const u16x8*)(bsrc + (it + 1) * 64 + r * 8);
            }
        }
        __syncthreads();
#pragma unroll
        for (int ks = 0; ks < 2; ++ks) {
            bf16x8 a[4], b[4];
#pragma unroll
            for (int i = 0; i < 4; ++i) {
                const int arow = wm * 64 + i * 16 + l15;
                a[i] = *(const bf16x8*)(Ac + arow * 64 + (((ks * 4 + sel) ^ (arow & 7)) * 8));
                const int brow = wn * 64 + i * 16 + l15;
                b[i] = *(const bf16x8*)(Bc + brow * 64 + (((ks * 4 + sel) ^ (brow & 7)) * 8));
            }
#pragma unroll
            for (int i = 0; i < 4; ++i)
#pragma unroll
                for (int j = 0; j < 4; ++j)
                    acc[i][j] = __builtin_amdgcn_mfma_f32_16x16x32_bf16(a[i], b[j], acc[i][j], 0, 0, 0);
        }
    }
    // epilogue: bf16 store
#pragma unroll
    for (int i = 0; i < 4; ++i)
#pragma unroll
        for (int j = 0; j < 4; ++j)
#pragma unroll
            for (int q = 0; q < 4; ++q) {
                const size_t m = m0 + wm * 64 + i * 16 + sel * 4 + q;
                const int col = n0 + wn * 64 + j * 16 + l15;
                Xg[m * 2048 + col] = f2bf(acc[i][j][q]);
            }
}

// ---------------------------------------------------------------------------
// One LSTM step: gates = Xg[t] + h @ Whh^T; cell; h stored swizzled.
// Grid 256 (nt8 x ut32), 512 thr = 8 waves (wm2 x wn4); wave owns [32r x 16c],
// K=512 unsplit; reg-staged double-buffered LDS; gate exchange via LDS dump.
// ---------------------------------------------------------------------------
__global__ __launch_bounds__(512) void lstm_step(
    const unsigned short* __restrict__ WhhImg,
    const unsigned short* __restrict__ Xg, const float* __restrict__ bsum,
    const unsigned short* __restrict__ h_in, unsigned short* __restrict__ h_out,
    float* __restrict__ c, int t) {
    __shared__ __align__(16) char smem[32768];
    // hs[2] @0,8K ; wsb[2] @16K,24K ; dump overlays 0..16K after K-loop
    float* dump = (float*)smem;          // [gate 4][row 64][cj 16]

    const int tid = threadIdx.x, bid = blockIdx.x;
    const int nt = bid & 7, ut = bid >> 3;
    const int n0 = nt * 64, u0 = ut * 16;
    const int wv = tid >> 6, lane = tid & 63;
    const int l15 = lane & 15, sel = lane >> 4;
    const int wm = wv >> 2, wn = wv & 3;         // wave tile: rows wm*32, gate wn
    const int srow = tid >> 3, sseg = tid & 7;
    const int wofs = srow * 128 + sseg * 16;     // byte offset in 8KB tile

    const unsigned short* hsrc = h_in + (size_t)(n0 + srow) * 512 + sseg * 8;
    const unsigned short* wsrc = WhhImg + ut * 32768 + srow * 512 + sseg * 8;

    f32x4 acc0 = (f32x4){0.f, 0.f, 0.f, 0.f};
    f32x4 acc1 = (f32x4){0.f, 0.f, 0.f, 0.f};

    u16x8 hv = *(const u16x8*)hsrc;
    u16x8 wr = *(const u16x8*)wsrc;

#pragma unroll
    for (int it = 0; it < 8; ++it) {
        char* H = smem + (it & 1) * 8192;
        char* W = smem + 16384 + (it & 1) * 8192;
        *(u16x8*)(H + wofs) = hv;
        *(u16x8*)(W + wofs) = wr;
        if (it < 7) {
            hv = *(const u16x8*)(hsrc + (it + 1) * 64);
            wr = *(const u16x8*)(wsrc + (it + 1) * 64);
        }
        __syncthreads();
#pragma unroll
        for (int ks = 0; ks < 2; ++ks) {
            const int ar0 = wm * 32 + l15, ar1 = ar0 + 16;
            const int br = wn * 16 + l15;
            bf16x8 a0 = *(const bf16x8*)(H + ar0 * 128 + (((ks * 4 + sel) ^ (ar0 & 7)) * 16));
            bf16x8 a1 = *(const bf16x8*)(H + ar1 * 128 + (((ks * 4 + sel) ^ (ar1 & 7)) * 16));
            bf16x8 b  = *(const bf16x8*)(W + br * 128 + (((ks * 4 + sel) ^ (br & 7)) * 16));
            acc0 = __builtin_amdgcn_mfma_f32_16x16x32_bf16(a0, b, acc0, 0, 0, 0);
            acc1 = __builtin_amdgcn_mfma_f32_16x16x32_bf16(a1, b, acc1, 0, 0, 0);
        }
    }
    __syncthreads();   // all reads of hs buffers done before dump overlays them

    // gate dump: wave (wm,wn) holds gate wn rows wm*32..+31
#pragma unroll
    for (int f = 0; f < 2; ++f)
#pragma unroll
        for (int q = 0; q < 4; ++q) {
            const int r = wm * 32 + f * 16 + sel * 4 + q;
            dump[wn * 1024 + r * 16 + l15] = (f ? acc1 : acc0)[q];
        }
    __syncthreads();

    // cell: 2 cells/thread
    const int crow = tid >> 4, cj = tid & 15;
    const float bI = bsum[u0 + cj];
    const float bF = bsum[512 + u0 + cj];
    const float bG = bsum[1024 + u0 + cj];
    const float bO = bsum[1536 + u0 + cj];
#pragma unroll
    for (int half = 0; half < 2; ++half) {
        const int r = crow + half * 32;
        const int n = n0 + r;
        const size_t xgr = ((size_t)t * 512 + n) * 2048 + u0 + cj;
        const float gi = dump[0 * 1024 + r * 16 + cj] + bf2f(Xg[xgr]) + bI;
        const float gf = dump[1 * 1024 + r * 16 + cj] + bf2f(Xg[xgr + 512]) + bF;
        const float gg = dump[2 * 1024 + r * 16 + cj] + bf2f(Xg[xgr + 1024]) + bG;
        const float go = dump[3 * 1024 + r * 16 + cj] + bf2f(Xg[xgr + 1536]) + bO;
        const size_t ci = (size_t)n * 512 + u0 + cj;
        const float I = sigmf(gi), F = sigmf(gf);
        const float G = tanh_fast(gg), O = sigmf(go);
        const float cn = F * c[ci] + I * G;
        c[ci] = cn;
        const int chunk = (ut * 2 + (cj >> 3)) ^ (n & 7);
        h_out[(size_t)n * 512 + chunk * 8 + (cj & 7)] = f2bf(O * tanh_fast(cn));
    }
}

// ---------------------------------------------------------------------------
// Head: pool (de-swizzle), fc1, fc2.
// ---------------------------------------------------------------------------
__global__ __launch_bounds__(256) void pool_kernel(
    const unsigned short* __restrict__ hfin, float* __restrict__ feat) {
    const int blk = blockIdx.x;
    const int b = blk >> 1, side = blk & 1;
    const int tid = threadIdx.x;
    for (int u = tid; u < Hn; u += 256) {
        float s = 0.0f, m = -1e30f;
#pragma unroll
        for (int ss = 0; ss < Sn; ++ss) {
            const int n = b * 32 + side * 16 + ss;
            const int chunk = (u >> 3) ^ (n & 7);
            float v = bf2f(hfin[(size_t)n * 512 + chunk * 8 + (u & 7)]);
            s += v;
            m = fmaxf(m, v);
        }
        feat[b * 2048 + side * 1024 + u] = s * (1.0f / 16.0f);
        feat[b * 2048 + side * 1024 + 512 + u] = m;
    }
}

__global__ __launch_bounds__(256) void fc1_kernel(
    const float* __restrict__ feat, const float* __restrict__ fc1w,
    const float* __restrict__ fc1b, float* __restrict__ z1) {
    __shared__ float fs[2048];
    __shared__ float red[256];
    const int b = blockIdx.x >> 4, oc = blockIdx.x & 15;
    const int tid = threadIdx.x;
    for (int k = tid; k < 2048; k += 256) fs[k] = feat[b * 2048 + k];
    __syncthreads();
    const int o = oc * 16 + (tid & 15);
    const int ks = (tid >> 4) * 128;
    const float4* w4 = (const float4*)(fc1w + (size_t)o * 2048 + ks);
    const float* fr = fs + ks;
    float p = 0.0f;
#pragma unroll 8
    for (int k = 0; k < 32; ++k) {
        float4 w = w4[k];
        p += fr[k * 4] * w.x + fr[k * 4 + 1] * w.y +
             fr[k * 4 + 2] * w.z + fr[k * 4 + 3] * w.w;
    }
    red[(tid & 15) * 16 + (tid >> 4)] = p;
    __syncthreads();
    if (tid < 16) {
        float z = fc1b[oc * 16 + tid];
#pragma unroll
        for (int j = 0; j < 16; ++j) z += red[tid * 16 + j];
        z1[b * 256 + oc * 16 + tid] = z;
    }
}

__global__ __launch_bounds__(256) void fc2_kernel(
    const float* __restrict__ z1, const float* __restrict__ fc2w,
    const float* __restrict__ fc2b, float* __restrict__ out) {
    __shared__ float sh[256];
    const int b = blockIdx.x, tid = threadIdx.x;
    sh[tid] = z1[b * 256 + tid] * fc2w[tid];
    __syncthreads();
    for (int s = 128; s > 0; s >>= 1) {
        if (tid < s) sh[tid] += sh[tid + s];
        __syncthreads();
    }
    if (tid == 0) out[b] = sigmf(sh[0] + fc2b[0]);
}

// ---------------------------------------------------------------------------
extern "C" void kernel_launch(void* const* d_in, const int* in_sizes, int n_in,
                              void* d_out, int out_size, void* d_ws, size_t ws_size,
                              hipStream_t stream) {
    const float* xf    = (const float*)d_in[0];
    const float* xa    = (const float*)d_in[1];
    const float* Wih_f = (const float*)d_in[2];
    const float* Whh_f = (const float*)d_in[3];
    const float* bih   = (const float*)d_in[4];
    const float* bhh   = (const float*)d_in[5];
    const float* fc1w  = (const float*)d_in[6];
    const float* fc1b  = (const float*)d_in[7];
    const float* fc2w  = (const float*)d_in[8];
    const float* fc2b  = (const float*)d_in[9];
    float* out = (float*)d_out;

    char* ws = (char*)d_ws;
    unsigned short* Wihb   = (unsigned short*)(ws + WS_WIHB);
    unsigned short* WhhImg = (unsigned short*)(ws + WS_WHH);
    float*          bsum   = (float*)(ws + WS_BSUM);
    unsigned short* hA     = (unsigned short*)(ws + WS_HA);
    unsigned short* hB     = (unsigned short*)(ws + WS_HB);
    float*          cbuf   = (float*)(ws + WS_C);
    float*          feat   = (float*)(ws + WS_FEAT);
    float*          z1     = (float*)(ws + WS_Z1);
    unsigned short* Xbf    = (unsigned short*)(ws + WS_XBF);
    unsigned short* Xg     = (unsigned short*)(ws + WS_XG);

    prep_w<<<dim3((PREPW_TOTAL + 255) / 256), dim3(256), 0, stream>>>(
        Wih_f, Whh_f, bih, bhh, Wihb, WhhImg, bsum, hA, cbuf);
    prep_x<<<dim3(8192), dim3(256), 0, stream>>>(xf, xa, Xbf);

    xg_gemm<<<dim3(4096), dim3(256), 0, stream>>>(Xbf, Wihb, Xg);

    for (int t = 0; t < Ln; ++t) {
        const unsigned short* hin = (t & 1) ? hB : hA;
        unsigned short* hout      = (t & 1) ? hA : hB;
        lstm_step<<<dim3(256), dim3(512), 0, stream>>>(
            WhhImg, Xg, bsum, hin, hout, cbuf, t);
    }
    // t=63 wrote hA
    pool_kernel<<<dim3(32), dim3(256), 0, stream>>>(hA, feat);
    fc1_kernel<<<dim3(256), dim3(256), 0, stream>>>(feat, fc1w, fc1b, z1);
    fc2_kernel<<<dim3(16), dim3(256), 0, stream>>>(z1, fc2w, fc2b, out);
}

// Round 8
// 443.007 us; speedup vs baseline: 7.6115x; 1.0388x over previous
//
#include <hip/hip_runtime.h>
#include <hip/hip_bf16.h>

// Problem constants
#define Bn 16
#define Sn 16
#define Ln 64
#define En 512
#define Hn 512
#define Nn 512   // B*2*S packed batch
#define G4 2048  // 4*H

typedef __bf16 bf16x8 __attribute__((ext_vector_type(8)));
typedef float f32x4 __attribute__((ext_vector_type(4)));
typedef unsigned short u16x8 __attribute__((ext_vector_type(8)));
typedef unsigned short u16x4 __attribute__((ext_vector_type(4)));

__device__ __forceinline__ unsigned short f2bf(float f) {
    union { float f; unsigned u; } v; v.f = f;
    unsigned r = v.u + 0x7FFFu + ((v.u >> 16) & 1u);   // RNE
    return (unsigned short)(r >> 16);
}
__device__ __forceinline__ float bf2f(unsigned short u) {
    union { unsigned u; float f; } v; v.u = ((unsigned)u) << 16;
    return v.f;
}
__device__ __forceinline__ float sigmf(float x) {
    return 1.0f / (1.0f + __expf(-x));
}
__device__ __forceinline__ float tanh_fast(float x) {
    x = fminf(fmaxf(x, -15.0f), 15.0f);
    float e = __expf(2.0f * x);
    return (e - 1.0f) / (e + 1.0f);
}

// ---------------------------------------------------------------------------
// ws layout (bytes)
// ---------------------------------------------------------------------------
#define WS_WIHB  0            // Wih bf16 [gcol 2048][k 512], chunk^(gcol&7) swizzle  2MB
#define WS_WHH   2097152      // Whh image [ut 32][grow 64][k 512], chunk^(grow&7)    2MB
#define WS_BSUM  4194304      // fp32 2048
#define WS_HA    4202496      // h bf16 [n 512][k 512], chunk^(n&7) swizzle   512KB
#define WS_HB    4726784      // 512KB
#define WS_C     5251072      // fp32 [n][u] 1MB
#define WS_FEAT  6299648      // 128KB
#define WS_Z1    6430720      // 16KB
#define WS_XBF   6447104      // x bf16 [m 32768][k 512], chunk^(m&7)  32MB
#define WS_XG    40001536     // Xg bf16 [m 32768][ut 32][u15 16][gate 4]  134MB

// prep_w work items
#define WI_CH 131072
#define WH_CH 131072
#define HZ 32768
#define CZ 65536
#define PREPW_TOTAL (WI_CH + WH_CH + 2048 + HZ + CZ)

__global__ __launch_bounds__(256) void prep_w(
    const float* __restrict__ Wih_f, const float* __restrict__ Whh_f,
    const float* __restrict__ bih, const float* __restrict__ bhh,
    unsigned short* __restrict__ Wihb, unsigned short* __restrict__ WhhImg,
    float* __restrict__ bsum, unsigned short* __restrict__ hA,
    float* __restrict__ c0) {
    int i = blockIdx.x * 256 + threadIdx.x;
    if (i < WI_CH) {
        int gcol = i >> 6, ch = i & 63;
        const float* s = Wih_f + (size_t)gcol * 512 + ch * 8;
        u16x8 w;
#pragma unroll
        for (int j = 0; j < 8; ++j) w[j] = f2bf(s[j]);
        *(u16x8*)(Wihb + (size_t)gcol * 512 + (ch ^ (gcol & 7)) * 8) = w;
    } else if (i < WI_CH + WH_CH) {
        int j = i - WI_CH;
        int g4row = j >> 6, ch = j & 63;
        int gate = g4row >> 9, unit = g4row & 511;
        int ut = unit >> 4, grow = gate * 16 + (unit & 15);
        const float* s = Whh_f + (size_t)g4row * 512 + ch * 8;
        u16x8 w;
#pragma unroll
        for (int k = 0; k < 8; ++k) w[k] = f2bf(s[k]);
        *(u16x8*)(WhhImg + ut * 32768 + grow * 512 + (ch ^ (grow & 7)) * 8) = w;
    } else if (i < WI_CH + WH_CH + 2048) {
        int j = i - (WI_CH + WH_CH);
        bsum[j] = bih[j] + bhh[j];
    } else if (i < WI_CH + WH_CH + 2048 + HZ) {
        int j = i - (WI_CH + WH_CH + 2048);
        u16x8 z = {0, 0, 0, 0, 0, 0, 0, 0};
        *(u16x8*)(hA + j * 8) = z;
    } else if (i < PREPW_TOTAL) {
        int j = i - (WI_CH + WH_CH + 2048 + HZ);
        f32x4 z = {0.f, 0.f, 0.f, 0.f};
        *(f32x4*)(c0 + j * 4) = z;
    }
}

// x -> bf16 [m][k] (m = t*512 + n), chunk^(m&7) swizzle.
__global__ __launch_bounds__(256) void prep_x(
    const float* __restrict__ xf, const float* __restrict__ xa,
    unsigned short* __restrict__ Xbf) {
    int j = blockIdx.x * 256 + threadIdx.x;
    int m = j >> 6, k8 = j & 63;
    int t = m >> 9, n = m & 511;
    int bb = n >> 5, rr = n & 31;
    const float* src = ((rr < Sn)
        ? xf + ((size_t)(bb * Sn + rr) * Ln + t) * En
        : xa + ((size_t)(bb * Sn + (rr - Sn)) * Ln + t) * En) + k8 * 8;
    float4 v0 = *(const float4*)src;
    float4 v1 = *(const float4*)(src + 4);
    u16x8 w;
    w[0] = f2bf(v0.x); w[1] = f2bf(v0.y); w[2] = f2bf(v0.z); w[3] = f2bf(v0.w);
    w[4] = f2bf(v1.x); w[5] = f2bf(v1.y); w[6] = f2bf(v1.z); w[7] = f2bf(v1.w);
    *(u16x8*)(Xbf + (size_t)m * 512 + (k8 ^ (m & 7)) * 8) = w;
}

// ---------------------------------------------------------------------------
// Xg = Xbf @ Wih^T : M=32768, N=2048, K=512. 128x128 tile, BK=64.
// XCD-chunked block map: 16 consecutive logical blocks share one A-panel and
// land on one XCD (L2 reuse). Staging writes are LINEAR (tid*16) ->
// conflict-free; images pre-swizzled so fragment reads XOR by row&7.
// Epilogue writes gate-packed layout [m][ut][u15][gate].
// ---------------------------------------------------------------------------
__global__ __launch_bounds__(256) void xg_gemm(
    const unsigned short* __restrict__ Xbf,
    const unsigned short* __restrict__ Wihb,
    unsigned short* __restrict__ Xg) {
    __shared__ __align__(16) unsigned short As[2][8192];  // [128 rows][64 k]
    __shared__ __align__(16) unsigned short Bs[2][8192];
    const int tid = threadIdx.x;
    const int p = blockIdx.x;
    const int L = (p & 7) * 512 + (p >> 3);   // bijective XCD-chunked map
    const int bx = L >> 4, by = L & 15;
    const size_t m0 = (size_t)bx * 128;
    const int n0 = by * 128;
    const int wv = tid >> 6, lane = tid & 63;
    const int l15 = lane & 15, sel = lane >> 4;
    const int wm = wv >> 1, wn = wv & 1;

    // staging: thread tid <-> LDS byte tid*16 (+r*4096); linear, conflict-free
    const int srow = tid >> 3;        // + r*32
    const int sseg = tid & 7;         // *8 u16
    const unsigned short* asrc = Xbf + (m0 + srow) * 512 + sseg * 8;
    const unsigned short* bsrc = Wihb + (size_t)(n0 + srow) * 512 + sseg * 8;

    f32x4 acc[4][4];
#pragma unroll
    for (int i = 0; i < 4; ++i)
#pragma unroll
        for (int j = 0; j < 4; ++j) acc[i][j] = (f32x4){0.f, 0.f, 0.f, 0.f};

    u16x8 ar[4], br[4];
#pragma unroll
    for (int r = 0; r < 4; ++r) {
        ar[r] = *(const u16x8*)(asrc + (size_t)r * 32 * 512);
        br[r] = *(const u16x8*)(bsrc + (size_t)r * 32 * 512);
    }

#pragma unroll 1
    for (int it = 0; it < 8; ++it) {
        unsigned short* Ac = As[it & 1];
        unsigned short* Bc = Bs[it & 1];
#pragma unroll
        for (int r = 0; r < 4; ++r) {
            *(u16x8*)((char*)Ac + r * 4096 + tid * 16) = ar[r];
            *(u16x8*)((char*)Bc + r * 4096 + tid * 16) = br[r];
        }
        if (it < 7) {
#pragma unroll
            for (int r = 0; r < 4; ++r) {
                ar[r] = *(const u16x8*)(asrc + (size_t)r * 32 * 512 + (it + 1) * 64);
                br[r] = *(const u16x8*)(bsrc + (size_t)r * 32 * 512 + (it + 1) * 64);
            }
        }
        __syncthreads();
#pragma unroll
        for (int ks = 0; ks < 2; ++ks) {
            bf16x8 a[4], b[4];
#pragma unroll
            for (int i = 0; i < 4; ++i) {
                const int arow = wm * 64 + i * 16 + l15;
                a[i] = *(const bf16x8*)(Ac + arow * 64 + (((ks * 4 + sel) ^ (arow & 7)) * 8));
                const int brow = wn * 64 + i * 16 + l15;
                b[i] = *(const bf16x8*)(Bc + brow * 64 + (((ks * 4 + sel) ^ (brow & 7)) * 8));
            }
#pragma unroll
            for (int i = 0; i < 4; ++i)
#pragma unroll
                for (int j = 0; j < 4; ++j)
                    acc[i][j] = __builtin_amdgcn_mfma_f32_16x16x32_bf16(a[i], b[j], acc[i][j], 0, 0, 0);
        }
    }
    // epilogue: gate-packed store. col = gate*512 + unit; here
    // gate = by>>2, ut = (by&3)*8 + wn*4 + j, u15 = l15.
    const int gate = by >> 2;
#pragma unroll
    for (int i = 0; i < 4; ++i)
#pragma unroll
        for (int j = 0; j < 4; ++j) {
            const int ut = (by & 3) * 8 + wn * 4 + j;
#pragma unroll
            for (int q = 0; q < 4; ++q) {
                const size_t m = m0 + wm * 64 + i * 16 + sel * 4 + q;
                Xg[m * 2048 + ut * 64 + l15 * 4 + gate] = f2bf(acc[i][j][q]);
            }
        }
}

// ---------------------------------------------------------------------------
// One LSTM step: gates = Xg[t] + h @ Whh^T; cell; h stored swizzled.
// Grid 256 (nt8 x ut32), 512 thr = 8 waves (wm2 x wn4); wave owns [32r x 16c],
// K=512 unsplit; reg-staged double-buffered LDS; gate exchange via LDS dump.
// ---------------------------------------------------------------------------
__global__ __launch_bounds__(512) void lstm_step(
    const unsigned short* __restrict__ WhhImg,
    const unsigned short* __restrict__ Xg, const float* __restrict__ bsum,
    const unsigned short* __restrict__ h_in, unsigned short* __restrict__ h_out,
    float* __restrict__ c, int t) {
    __shared__ __align__(16) char smem[32768];
    // hs[2] @0,8K ; wsb[2] @16K,24K ; dump overlays 0..16K after K-loop
    float* dump = (float*)smem;          // [gate 4][row 64][cj 16]

    const int tid = threadIdx.x, bid = blockIdx.x;
    const int nt = bid & 7, ut = bid >> 3;
    const int n0 = nt * 64, u0 = ut * 16;
    const int wv = tid >> 6, lane = tid & 63;
    const int l15 = lane & 15, sel = lane >> 4;
    const int wm = wv >> 2, wn = wv & 3;         // wave tile: rows wm*32, gate wn
    const int srow = tid >> 3, sseg = tid & 7;
    const int wofs = srow * 128 + sseg * 16;     // == tid*16, linear

    const unsigned short* hsrc = h_in + (size_t)(n0 + srow) * 512 + sseg * 8;
    const unsigned short* wsrc = WhhImg + ut * 32768 + srow * 512 + sseg * 8;

    f32x4 acc0 = (f32x4){0.f, 0.f, 0.f, 0.f};
    f32x4 acc1 = (f32x4){0.f, 0.f, 0.f, 0.f};

    u16x8 hv = *(const u16x8*)hsrc;
    u16x8 wr = *(const u16x8*)wsrc;

#pragma unroll
    for (int it = 0; it < 8; ++it) {
        char* H = smem + (it & 1) * 8192;
        char* W = smem + 16384 + (it & 1) * 8192;
        *(u16x8*)(H + wofs) = hv;
        *(u16x8*)(W + wofs) = wr;
        if (it < 7) {
            hv = *(const u16x8*)(hsrc + (it + 1) * 64);
            wr = *(const u16x8*)(wsrc + (it + 1) * 64);
        }
        __syncthreads();
#pragma unroll
        for (int ks = 0; ks < 2; ++ks) {
            const int ar0 = wm * 32 + l15, ar1 = ar0 + 16;
            const int br = wn * 16 + l15;
            bf16x8 a0 = *(const bf16x8*)(H + ar0 * 128 + (((ks * 4 + sel) ^ (ar0 & 7)) * 16));
            bf16x8 a1 = *(const bf16x8*)(H + ar1 * 128 + (((ks * 4 + sel) ^ (ar1 & 7)) * 16));
            bf16x8 b  = *(const bf16x8*)(W + br * 128 + (((ks * 4 + sel) ^ (br & 7)) * 16));
            acc0 = __builtin_amdgcn_mfma_f32_16x16x32_bf16(a0, b, acc0, 0, 0, 0);
            acc1 = __builtin_amdgcn_mfma_f32_16x16x32_bf16(a1, b, acc1, 0, 0, 0);
        }
    }
    __syncthreads();   // all reads of hs buffers done before dump overlays them

    // gate dump: wave (wm,wn) holds gate wn rows wm*32..+31
#pragma unroll
    for (int f = 0; f < 2; ++f)
#pragma unroll
        for (int q = 0; q < 4; ++q) {
            const int r = wm * 32 + f * 16 + sel * 4 + q;
            dump[wn * 1024 + r * 16 + l15] = (f ? acc1 : acc0)[q];
        }
    __syncthreads();

    // cell: 2 cells/thread; Xg gate-packed read (one 8B load per cell)
    const int crow = tid >> 4, cj = tid & 15;
    const float bI = bsum[u0 + cj];
    const float bF = bsum[512 + u0 + cj];
    const float bG = bsum[1024 + u0 + cj];
    const float bO = bsum[1536 + u0 + cj];
#pragma unroll
    for (int half = 0; half < 2; ++half) {
        const int r = crow + half * 32;
        const int n = n0 + r;
        const u16x4 xv = *(const u16x4*)(Xg + ((size_t)t * 512 + n) * 2048 + ut * 64 + cj * 4);
        const float gi = dump[0 * 1024 + r * 16 + cj] + bf2f(xv[0]) + bI;
        const float gf = dump[1 * 1024 + r * 16 + cj] + bf2f(xv[1]) + bF;
        const float gg = dump[2 * 1024 + r * 16 + cj] + bf2f(xv[2]) + bG;
        const float go = dump[3 * 1024 + r * 16 + cj] + bf2f(xv[3]) + bO;
        const size_t ci = (size_t)n * 512 + u0 + cj;
        const float I = sigmf(gi), F = sigmf(gf);
        const float G = tanh_fast(gg), O = sigmf(go);
        const float cn = F * c[ci] + I * G;
        c[ci] = cn;
        const int chunk = (ut * 2 + (cj >> 3)) ^ (n & 7);
        h_out[(size_t)n * 512 + chunk * 8 + (cj & 7)] = f2bf(O * tanh_fast(cn));
    }
}

// ---------------------------------------------------------------------------
// Head: pool (de-swizzle), fc1, fc2.
// ---------------------------------------------------------------------------
__global__ __launch_bounds__(256) void pool_kernel(
    const unsigned short* __restrict__ hfin, float* __restrict__ feat) {
    const int blk = blockIdx.x;
    const int b = blk >> 1, side = blk & 1;
    const int tid = threadIdx.x;
    for (int u = tid; u < Hn; u += 256) {
        float s = 0.0f, m = -1e30f;
#pragma unroll
        for (int ss = 0; ss < Sn; ++ss) {
            const int n = b * 32 + side * 16 + ss;
            const int chunk = (u >> 3) ^ (n & 7);
            float v = bf2f(hfin[(size_t)n * 512 + chunk * 8 + (u & 7)]);
            s += v;
            m = fmaxf(m, v);
        }
        feat[b * 2048 + side * 1024 + u] = s * (1.0f / 16.0f);
        feat[b * 2048 + side * 1024 + 512 + u] = m;
    }
}

__global__ __launch_bounds__(256) void fc1_kernel(
    const float* __restrict__ feat, const float* __restrict__ fc1w,
    const float* __restrict__ fc1b, float* __restrict__ z1) {
    __shared__ float fs[2048];
    __shared__ float red[256];
    const int b = blockIdx.x >> 4, oc = blockIdx.x & 15;
    const int tid = threadIdx.x;
    for (int k = tid; k < 2048; k += 256) fs[k] = feat[b * 2048 + k];
    __syncthreads();
    const int o = oc * 16 + (tid & 15);
    const int ks = (tid >> 4) * 128;
    const float4* w4 = (const float4*)(fc1w + (size_t)o * 2048 + ks);
    const float* fr = fs + ks;
    float p = 0.0f;
#pragma unroll 8
    for (int k = 0; k < 32; ++k) {
        float4 w = w4[k];
        p += fr[k * 4] * w.x + fr[k * 4 + 1] * w.y +
             fr[k * 4 + 2] * w.z + fr[k * 4 + 3] * w.w;
    }
    red[(tid & 15) * 16 + (tid >> 4)] = p;
    __syncthreads();
    if (tid < 16) {
        float z = fc1b[oc * 16 + tid];
#pragma unroll
        for (int j = 0; j < 16; ++j) z += red[tid * 16 + j];
        z1[b * 256 + oc * 16 + tid] = z;
    }
}

__global__ __launch_bounds__(256) void fc2_kernel(
    const float* __restrict__ z1, const float* __restrict__ fc2w,
    const float* __restrict__ fc2b, float* __restrict__ out) {
    __shared__ float sh[256];
    const int b = blockIdx.x, tid = threadIdx.x;
    sh[tid] = z1[b * 256 + tid] * fc2w[tid];
    __syncthreads();
    for (int s = 128; s > 0; s >>= 1) {
        if (tid < s) sh[tid] += sh[tid + s];
        __syncthreads();
    }
    if (tid == 0) out[b] = sigmf(sh[0] + fc2b[0]);
}

// ---------------------------------------------------------------------------
extern "C" void kernel_launch(void* const* d_in, const int* in_sizes, int n_in,
                              void* d_out, int out_size, void* d_ws, size_t ws_size,
                              hipStream_t stream) {
    const float* xf    = (const float*)d_in[0];
    const float* xa    = (const float*)d_in[1];
    const float* Wih_f = (const float*)d_in[2];
    const float* Whh_f = (const float*)d_in[3];
    const float* bih   = (const float*)d_in[4];
    const float* bhh   = (const float*)d_in[5];
    const float* fc1w  = (const float*)d_in[6];
    const float* fc1b  = (const float*)d_in[7];
    const float* fc2w  = (const float*)d_in[8];
    const float* fc2b  = (const float*)d_in[9];
    float* out = (float*)d_out;

    char* ws = (char*)d_ws;
    unsigned short* Wihb   = (unsigned short*)(ws + WS_WIHB);
    unsigned short* WhhImg = (unsigned short*)(ws + WS_WHH);
    float*          bsum   = (float*)(ws + WS_BSUM);
    unsigned short* hA     = (unsigned short*)(ws + WS_HA);
    unsigned short* hB     = (unsigned short*)(ws + WS_HB);
    float*          cbuf   = (float*)(ws + WS_C);
    float*          feat   = (float*)(ws + WS_FEAT);
    float*          z1     = (float*)(ws + WS_Z1);
    unsigned short* Xbf    = (unsigned short*)(ws + WS_XBF);
    unsigned short* Xg     = (unsigned short*)(ws + WS_XG);

    prep_w<<<dim3((PREPW_TOTAL + 255) / 256), dim3(256), 0, stream>>>(
        Wih_f, Whh_f, bih, bhh, Wihb, WhhImg, bsum, hA, cbuf);
    prep_x<<<dim3(8192), dim3(256), 0, stream>>>(xf, xa, Xbf);

    xg_gemm<<<dim3(4096), dim3(256), 0, stream>>>(Xbf, Wihb, Xg);

    for (int t = 0; t < Ln; ++t) {
        const unsigned short* hin = (t & 1) ? hB : hA;
        unsigned short* hout      = (t & 1) ? hA : hB;
        lstm_step<<<dim3(256), dim3(512), 0, stream>>>(
            WhhImg, Xg, bsum, hin, hout, cbuf, t);
    }
    // t=63 wrote hA
    pool_kernel<<<dim3(32), dim3(256), 0, stream>>>(hA, feat);
    fc1_kernel<<<dim3(256), dim3(256), 0, stream>>>(feat, fc1w, fc1b, z1);
    fc2_kernel<<<dim3(16), dim3(256), 0, stream>>>(z1, fc2w, fc2b, out);
}